// Round 5
// baseline (3681.570 us; speedup 1.0000x reference)
//
#include <hip/hip_runtime.h>
#include <stdint.h>

// Problem constants
#define VOCAB  50000
#define EMBD   256
#define HIDD   512
#define G4     2048   // 4*HID
#define NBAT   256
#define TSEQ   512

// ---- workspace layout (bytes) ----
#define O_P2    0ull            // P2[v][j*4+g] bf16 : VOCAB*G4*2 = 204,800,000
#define O_EMBT  204800000ull    // emb bf16 [V][E] (dead after k_proj; flags live here)
#define O_WIH   230400000ull    // W_ih bf16 [G4][E]
#define O_WHH   231448576ull    // W_hh bf16 [G4][H]
#define O_TOKT  233545728ull    // tokT int [2][T][N]
#define O_HBUF  234594304ull    // h bf16 [2 lstm][2 phase][N][H] = 1 MiB
#define WS_NEED 235643136ull
#define O_FLAGS O_EMBT          // 512 flags x 256B stride = 128 KB, zeroed post-k_proj

typedef __bf16 bf16x8  __attribute__((ext_vector_type(8)));
typedef __bf16 bf16x16 __attribute__((ext_vector_type(16)));
typedef float  f32x4   __attribute__((ext_vector_type(4)));
typedef unsigned long long ullx2 __attribute__((ext_vector_type(2)));

__device__ __forceinline__ unsigned short f2bf(float x) {
  unsigned u = __float_as_uint(x);
  u = (u + 0x7fffu + ((u >> 16) & 1u)) >> 16;   // RNE
  return (unsigned short)u;
}
__device__ __forceinline__ float b2f(unsigned short b) {
  return __uint_as_float(((unsigned)b) << 16);
}
__device__ __forceinline__ float sigf(float x) {
  float e = __builtin_amdgcn_exp2f(-1.4426950408889634f * x);
  return __builtin_amdgcn_rcpf(1.0f + e);
}
__device__ __forceinline__ float tanhf_(float x) {
  float e = __builtin_amdgcn_exp2f(-2.8853900817779268f * x);
  return 2.0f * __builtin_amdgcn_rcpf(1.0f + e) - 1.0f;
}

// ------------------------------------------------------------------
// K1: prep — bf16 converts, token transpose, zero h
// ------------------------------------------------------------------
__global__ void k_prep(const float* __restrict__ emb, const float* __restrict__ wih,
                       const float* __restrict__ whh, const int* __restrict__ tok1,
                       const int* __restrict__ tok2, unsigned short* __restrict__ embT,
                       unsigned short* __restrict__ wihb, unsigned short* __restrict__ whhb,
                       int* __restrict__ tokT, unsigned* __restrict__ hz)
{
  const int stride = gridDim.x * blockDim.x;
  const int id0 = blockIdx.x * blockDim.x + threadIdx.x;
  for (int i = id0; i < VOCAB * EMBD; i += stride) embT[i] = f2bf(emb[i]);
  for (int i = id0; i < G4 * EMBD; i += stride)    wihb[i] = f2bf(wih[i]);
  for (int i = id0; i < G4 * HIDD; i += stride)    whhb[i] = f2bf(whh[i]);
  for (int i = id0; i < 2 * TSEQ * NBAT; i += stride) {
    int l = i >> 17, t = (i >> 8) & 511, n = i & 255;
    tokT[i] = (l ? tok2 : tok1)[n * TSEQ + t];
  }
  for (int i = id0; i < 262144; i += stride) hz[i] = 0u;   // zero h buffers (1 MiB)
}

// ------------------------------------------------------------------
// K1b: zero progress flags (after k_proj; flags overlap dead embT region)
// ------------------------------------------------------------------
__global__ void k_zero(unsigned* __restrict__ flags)
{
  const int i = blockIdx.x * blockDim.x + threadIdx.x;
  if (i < 65536) flags[i] = 0u;   // 256 KB
}

// ------------------------------------------------------------------
// K2: vocab projection  P2[v][j*4+g] = emb[v]·W_ih[g*512+j] + b_ih + b_hh
// (unchanged — round-1 correctness-verified)
// ------------------------------------------------------------------
__global__ __launch_bounds__(256) void
k_proj(const unsigned short* __restrict__ embT, const unsigned short* __restrict__ wihb,
       const float* __restrict__ bih, const float* __restrict__ bhh,
       unsigned short* __restrict__ P2)
{
  const int l  = threadIdx.x & 63;
  const int w  = threadIdx.x >> 6;
  const int n0 = blockIdx.x * 128 + (w & 1) * 64;
  const int m0 = blockIdx.y * 128 + (w >> 1) * 64;
  const int lq = l >> 4, lc = l & 15;

  f32x4 acc[4][4];
  #pragma unroll
  for (int a = 0; a < 4; ++a)
    #pragma unroll
    for (int b = 0; b < 4; ++b) acc[a][b] = (f32x4){0.f, 0.f, 0.f, 0.f};

  const uint8_t* eb = (const uint8_t*)embT;
  const uint8_t* wb = (const uint8_t*)wihb;
  #pragma unroll
  for (int ks = 0; ks < 8; ++ks) {
    const int koff = ks * 64 + lq * 16;
    bf16x8 a[4], b[4];
    #pragma unroll
    for (int mt = 0; mt < 4; ++mt) {
      int row = m0 + mt * 16 + lc; if (row >= VOCAB) row = VOCAB - 1;
      a[mt] = *(const bf16x8*)(eb + (size_t)row * 512 + koff);
    }
    #pragma unroll
    for (int nt = 0; nt < 4; ++nt) {
      int g = n0 + nt * 16 + lc;
      b[nt] = *(const bf16x8*)(wb + (size_t)g * 512 + koff);
    }
    #pragma unroll
    for (int mt = 0; mt < 4; ++mt)
      #pragma unroll
      for (int nt = 0; nt < 4; ++nt)
        acc[mt][nt] = __builtin_amdgcn_mfma_f32_16x16x32_bf16(a[mt], b[nt], acc[mt][nt], 0, 0, 0);
  }

  #pragma unroll
  for (int mt = 0; mt < 4; ++mt)
    #pragma unroll
    for (int r = 0; r < 4; ++r) {
      const int vrow = m0 + mt * 16 + lq * 4 + r;
      if (vrow < VOCAB) {
        #pragma unroll
        for (int nt = 0; nt < 4; ++nt) {
          const int gcol = n0 + nt * 16 + lc;
          float v = acc[mt][nt][r] + bih[gcol] + bhh[gcol];
          const int colp = ((gcol & 511) << 2) | (gcol >> 9);  // [j][g] permuted
          P2[(size_t)vrow * 2048 + colp] = f2bf(v);
        }
      }
    }
}

// ------------------------------------------------------------------
// stage 16 h-rows (16 KB) global->LDS in paired-chunk split layout:
// LDS(row, ks, q) at row*1024 + q*256 + ((ks>>1)^(row&7))*32 + (ks&1)*16
//   <-> global bytes row*1024 + ks*64 + q*16    (k = ks*32 + q*8 + j)
// ------------------------------------------------------------------
__device__ __forceinline__ void stage_h16(uint8_t* dst, const uint8_t* src_base, int tid)
{
  const int row = tid >> 4, rem = tid & 15, q = rem >> 2, g4 = rem & 3;
  const uint8_t* s0 = src_base + (size_t)row * 1024 + q * 16;
  unsigned long long v[8];
  #pragma unroll
  for (int j = 0; j < 4; ++j) {
    const int ks = g4 * 4 + j;
    v[2*j]   = __hip_atomic_load((const unsigned long long*)(s0 + ks * 64),
                                 __ATOMIC_RELAXED, __HIP_MEMORY_SCOPE_AGENT);
    v[2*j+1] = __hip_atomic_load((const unsigned long long*)(s0 + ks * 64 + 8),
                                 __ATOMIC_RELAXED, __HIP_MEMORY_SCOPE_AGENT);
  }
  uint8_t* d0 = dst + (size_t)row * 1024 + q * 256;
  #pragma unroll
  for (int j = 0; j < 4; ++j) {
    const int ks = g4 * 4 + j;
    ullx2 p; p.x = v[2*j]; p.y = v[2*j+1];
    *(ullx2*)(d0 + (((ks >> 1) ^ (row & 7)) * 32) + (ks & 1) * 16) = p;
  }
}

// ------------------------------------------------------------------
// K3: persistent LSTM scan, two-stream pipelined. 256 blocks x 256 thr.
// block = (lstm, mg: 32 rows, jb: 32 cols); streams A/B = 16-row halves,
// phase-alternated so each stream's MALL sync hides under the other's
// compute. W_hh slice 128KB + 2x16KB stream regions = 160KB LDS.
// ------------------------------------------------------------------
#define HL 131072

__global__ __launch_bounds__(256, 1) void
k_lstm(const uint8_t* __restrict__ P2, const int* __restrict__ tokT,
       const uint8_t* __restrict__ whh, uint8_t* __restrict__ hbuf,
       unsigned* __restrict__ flags)
{
  __shared__ __align__(16) uint8_t smem[163840];
  const int tid  = threadIdx.x;
  const int l    = tid & 63;
  const int w    = tid >> 6;        // wave = gate
  const int bid  = blockIdx.x;
  const int jb   = bid & 15;
  const int mg   = (bid >> 4) & 7;
  const int lstm = bid >> 7;
  const int grp  = bid >> 4;        // 16 blocks per (lstm, mg) group
  const int m0   = mg * 32;
  const int j0   = jb * 32;

  // ---- stage W_hh gate-slice once: LDS row R = g*32+jl <-> W row g*512+j0+jl
  for (int i = 0; i < 32; ++i) {
    const int G = i * 256 + tid;            // 16B chunk id 0..8191
    const int R = G >> 6, c = G & 63;
    const int ks = c >> 2, q = c & 3;
    const uint8_t* src = whh + (size_t)((R >> 5) * 512 + j0 + (R & 31)) * 1024 + (size_t)c * 16;
    const uint4 v = *(const uint4*)src;
    *(uint4*)(smem + (size_t)R * 1024 + q * 256 + (((ks >> 1) ^ (R & 7)) * 32) + (ks & 1) * 16) = v;
  }

  const size_t hslot = (size_t)NBAT * HIDD * 2;   // 262144 B
  const int arow = l & 15;          // MFMA A-row / B-col
  const int q4   = l >> 4;          // k-quad
  const int erow = tid >> 4;        // epilogue row 0..15
  const int ecg  = tid & 15;        // epilogue col pair

  float cA0 = 0.f, cA1 = 0.f, cB0 = 0.f, cB1 = 0.f;
  uint4 xqA, xqB;

  // ---- prime stream A for t=0: h(-1)=zeros (slot 0) + xg_A(0) ----
  {
    const int tok = tokT[(lstm * TSEQ + 0) * NBAT + m0 + erow];
    xqA = *(const uint4*)(P2 + (size_t)tok * 4096 + (size_t)(j0 + ecg * 2) * 8);
    stage_h16(smem + HL, hbuf + (size_t)(lstm * 2) * hslot + (size_t)m0 * 1024, tid);
  }

  for (int ph = 0; ph < 2 * TSEQ; ++ph) {
    const int s = ph & 1, t = ph >> 1;
    uint8_t* hb = smem + HL + s * 16384;

    __syncthreads();   // staged h_s visible; region exclusive to this phase

    // ---- GEMM: gates[16x(4x32)] = h_s[16x512] . W^T  (16x16x32 MFMA) ----
    f32x4 acc0 = {0.f,0.f,0.f,0.f}, acc1 = {0.f,0.f,0.f,0.f};
    {
      const uint8_t* abase  = hb + (size_t)arow * 1024 + q4 * 256;
      const uint8_t* b0base = smem + (size_t)(w * 32 + arow) * 1024 + q4 * 256;
      const uint8_t* b1base = b0base + 16 * 1024;
      const int sw = arow & 7;
      #pragma unroll
      for (int ksp = 0; ksp < 8; ++ksp) {
        const int off = (ksp ^ sw) * 32;
        const bf16x16 av = *(const bf16x16*)(abase + off);
        const bf16x16 b0 = *(const bf16x16*)(b0base + off);
        const bf16x16 b1 = *(const bf16x16*)(b1base + off);
        const bf16x8 al = __builtin_shufflevector(av, av, 0,1,2,3,4,5,6,7);
        const bf16x8 ah = __builtin_shufflevector(av, av, 8,9,10,11,12,13,14,15);
        const bf16x8 b0l = __builtin_shufflevector(b0, b0, 0,1,2,3,4,5,6,7);
        const bf16x8 b0h = __builtin_shufflevector(b0, b0, 8,9,10,11,12,13,14,15);
        const bf16x8 b1l = __builtin_shufflevector(b1, b1, 0,1,2,3,4,5,6,7);
        const bf16x8 b1h = __builtin_shufflevector(b1, b1, 8,9,10,11,12,13,14,15);
        acc0 = __builtin_amdgcn_mfma_f32_16x16x32_bf16(al, b0l, acc0, 0, 0, 0);
        acc1 = __builtin_amdgcn_mfma_f32_16x16x32_bf16(al, b1l, acc1, 0, 0, 0);
        acc0 = __builtin_amdgcn_mfma_f32_16x16x32_bf16(ah, b0h, acc0, 0, 0, 0);
        acc1 = __builtin_amdgcn_mfma_f32_16x16x32_bf16(ah, b1h, acc1, 0, 0, 0);
      }
    }
    __syncthreads();   // GEMM reads done; h_s region reusable as gate buffer

    // ---- gate buffer: f32 gb[16 rows][32 cols][4 gates] (8 KB) ----
    {
      float* gb = (float*)hb;
      #pragma unroll
      for (int r = 0; r < 4; ++r) {
        gb[((q4 * 4 + r) * 32 + arow) * 4 + w]      = acc0[r];
        gb[((q4 * 4 + r) * 32 + 16 + arow) * 4 + w] = acc1[r];
      }
    }
    __syncthreads();   // gate buffer ready

    // ---- epilogue: 2 cells/thread, lane-local nonlinearity ----
    {
      const float* gb = (const float*)hb;
      const int go = (erow * 32 + ecg * 2) * 4;
      const f32x4 p0 = *(const f32x4*)(gb + go);       // col 2*ecg   : i,f,g,o
      const f32x4 p1 = *(const f32x4*)(gb + go + 4);   // col 2*ecg+1
      unsigned short xv[8];
      const uint4 xqs = s ? xqB : xqA;
      *(uint4*)xv = xqs;
      float c0 = s ? cB0 : cA0;
      float c1 = s ? cB1 : cA1;
      const float i0 = sigf(p0[0] + b2f(xv[0]));
      const float f0 = sigf(p0[1] + b2f(xv[1]));
      const float g0 = tanhf_(p0[2] + b2f(xv[2]));
      const float o0 = sigf(p0[3] + b2f(xv[3]));
      c0 = f0 * c0 + i0 * g0;
      const float h0 = o0 * tanhf_(c0);
      const float i1 = sigf(p1[0] + b2f(xv[4]));
      const float f1 = sigf(p1[1] + b2f(xv[5]));
      const float g1 = tanhf_(p1[2] + b2f(xv[6]));
      const float o1 = sigf(p1[3] + b2f(xv[7]));
      c1 = f1 * c1 + i1 * g1;
      const float h1 = o1 * tanhf_(c1);
      if (s) { cB0 = c0; cB1 = c1; } else { cA0 = c0; cA1 = c1; }
      const unsigned hp = (unsigned)f2bf(h0) | ((unsigned)f2bf(h1) << 16);
      uint8_t* hdst = hbuf + (size_t)(lstm * 2 + ((t + 1) & 1)) * hslot
                    + (size_t)(m0 + s * 16 + erow) * 1024 + (size_t)(j0 + ecg * 2) * 2;
      __hip_atomic_store((unsigned*)hdst, hp, __ATOMIC_RELAXED, __HIP_MEMORY_SCOPE_AGENT);
    }
    __syncthreads();   // drain: all h stores at coherence point

    if (tid == 0 && t < TSEQ - 1)
      __hip_atomic_store(flags + (size_t)(bid * 2 + s) * 64, (unsigned)(t + 1),
                         __ATOMIC_RELAXED, __HIP_MEMORY_SCOPE_AGENT);

    // ---- tail: prepare NEXT stream (poll + prefetch, hidden by this phase) ----
    if (ph < 2 * TSEQ - 1) {
      const int ns = s ^ 1;
      const int tn = t + s;            // A-tail preps B(t); B-tail preps A(t+1)
      // xg + token for next phase (independent of poll — issue first)
      const int tok = tokT[(lstm * TSEQ + tn) * NBAT + m0 + ns * 16 + erow];
      const uint4 nx = *(const uint4*)(P2 + (size_t)tok * 4096 + (size_t)(j0 + ecg * 2) * 8);
      if (ns) xqB = nx; else xqA = nx;
      // per-wave poll: peers' stream-ns flag must reach tn
      {
        const unsigned tgt = (unsigned)tn;
        const unsigned* fp = flags + (size_t)(((grp << 4) + (l & 15)) * 2 + ns) * 64;
        int guard = 0;
        for (;;) {
          const unsigned v = __hip_atomic_load(fp, __ATOMIC_RELAXED, __HIP_MEMORY_SCOPE_AGENT);
          if (__all((int)(v >= tgt))) break;
          __builtin_amdgcn_s_sleep(1);
          if (++guard > 400000) break;   // fail visible, not hung
        }
      }
      // stage h_ns(tn-1) from slot (tn&1) into its LDS region (region is dead)
      stage_h16(smem + HL + ns * 16384,
                hbuf + (size_t)(lstm * 2 + (tn & 1)) * hslot + (size_t)(m0 + ns * 16) * 1024,
                tid);
    }
  }
}

// ------------------------------------------------------------------
// K4: h1*h2 -> logits -> softmax. one wave per batch row.
// ------------------------------------------------------------------
__global__ __launch_bounds__(64) void
k_fc(const uint8_t* __restrict__ hbuf, const float* __restrict__ wfc,
     const float* __restrict__ bfc, float* __restrict__ out)
{
  const int n = blockIdx.x, l = threadIdx.x;
  const unsigned short* h1 = (const unsigned short*)(hbuf) + (size_t)n * HIDD;
  const unsigned short* h2 = (const unsigned short*)(hbuf + 2 * (size_t)NBAT * HIDD * 2) + (size_t)n * HIDD;
  float s0 = 0.f, s1 = 0.f;
  for (int j = l; j < HIDD; j += 64) {
    float hv = b2f(h1[j]) * b2f(h2[j]);
    s0 += hv * wfc[j];
    s1 += hv * wfc[HIDD + j];
  }
  #pragma unroll
  for (int off = 32; off > 0; off >>= 1) {
    s0 += __shfl_down(s0, off, 64);
    s1 += __shfl_down(s1, off, 64);
  }
  if (l == 0) {
    s0 += bfc[0]; s1 += bfc[1];
    float m  = fmaxf(s0, s1);
    float e0 = __builtin_amdgcn_exp2f((s0 - m) * 1.4426950408889634f);
    float e1 = __builtin_amdgcn_exp2f((s1 - m) * 1.4426950408889634f);
    float inv = 1.0f / (e0 + e1);
    out[n * 2 + 0] = e0 * inv;
    out[n * 2 + 1] = e1 * inv;
  }
}

// ------------------------------------------------------------------
extern "C" void kernel_launch(void* const* d_in, const int* in_sizes, int n_in,
                              void* d_out, int out_size, void* d_ws, size_t ws_size,
                              hipStream_t stream) {
  (void)in_sizes; (void)n_in; (void)out_size;
  if (ws_size < WS_NEED) return;   // fail visibly rather than scribble OOB

  const int*   tok1 = (const int*)d_in[0];
  const int*   tok2 = (const int*)d_in[1];
  const float* emb  = (const float*)d_in[2];
  const float* wih  = (const float*)d_in[3];
  const float* whh  = (const float*)d_in[4];
  const float* bih  = (const float*)d_in[5];
  const float* bhh  = (const float*)d_in[6];
  const float* wfc  = (const float*)d_in[7];
  const float* bfc  = (const float*)d_in[8];
  float* out = (float*)d_out;

  uint8_t* ws = (uint8_t*)d_ws;
  unsigned short* P2    = (unsigned short*)(ws + O_P2);
  unsigned short* embT  = (unsigned short*)(ws + O_EMBT);
  unsigned short* wihb  = (unsigned short*)(ws + O_WIH);
  unsigned short* whhb  = (unsigned short*)(ws + O_WHH);
  int*            tokT  = (int*)(ws + O_TOKT);
  uint8_t*        hbuf  = ws + O_HBUF;
  unsigned*       flags = (unsigned*)(ws + O_FLAGS);

  k_prep<<<1024, 256, 0, stream>>>(emb, wih, whh, tok1, tok2, embT, wihb, whhb,
                                   tokT, (unsigned*)hbuf);
  k_proj<<<dim3(16, 391), 256, 0, stream>>>(embT, wihb, bih, bhh, P2);
  k_zero<<<256, 256, 0, stream>>>(flags);   // embT dead after k_proj

  {
    const uint8_t* p2p = (const uint8_t*)P2;
    const int*     tkp = tokT;
    const uint8_t* whp = (const uint8_t*)whhb;
    uint8_t*       hbp = hbuf;
    unsigned*      flp = flags;
    void* args[5] = {(void*)&p2p, (void*)&tkp, (void*)&whp, (void*)&hbp, (void*)&flp};
    hipError_t e = hipLaunchCooperativeKernel((void*)k_lstm, dim3(256), dim3(256),
                                              args, 0, stream);
    if (e != hipSuccess) {
      (void)hipGetLastError();  // clear; fall back (256 blocks @ 1/CU are co-resident)
      k_lstm<<<256, 256, 0, stream>>>(p2p, tkp, whp, hbp, flp);
    }
  }

  k_fc<<<256, 64, 0, stream>>>(hbuf, wfc, bfc, out);
}

// Round 6
// 2457.764 us; speedup vs baseline: 1.4979x; 1.4979x over previous
//
#include <hip/hip_runtime.h>
#include <stdint.h>

// Problem constants
#define VOCAB  50000
#define EMBD   256
#define HIDD   512
#define G4     2048   // 4*HID
#define NBAT   256
#define TSEQ   512

// ---- workspace layout (bytes) ----
#define O_P2    0ull            // P2[v][j*4+g] bf16 : VOCAB*G4*2 = 204,800,000
#define O_EMBT  204800000ull    // emb bf16 [V][E] (dead after k_proj; hseq lives here)
#define O_WIH   230400000ull    // W_ih bf16 [G4][E]
#define O_WHH   231448576ull    // W_hh bf16 [G4][H]
#define O_TOKT  233545728ull    // tokT int [2][T][N]
#define WS_NEED 235643136ull
// rotating h exchange: [2 lstm][8 slots][N][H] bf16 = 16 x 262144 B = 4 MiB
#define O_HSEQ  O_EMBT
#define HSLOT   262144ull
#define SENT    0xFFFFFFFFFFFFFFFFull   // 4x bf16 -NaN: unreachable from finite h

typedef __bf16 bf16x8 __attribute__((ext_vector_type(8)));
typedef float  f32x4  __attribute__((ext_vector_type(4)));
typedef float  f32x16 __attribute__((ext_vector_type(16)));

__device__ __forceinline__ unsigned short f2bf(float x) {
  unsigned u = __float_as_uint(x);
  u = (u + 0x7fffu + ((u >> 16) & 1u)) >> 16;   // RNE
  return (unsigned short)u;
}
__device__ __forceinline__ float b2f(unsigned short b) {
  return __uint_as_float(((unsigned)b) << 16);
}
__device__ __forceinline__ float sigf(float x) {
  float e = __builtin_amdgcn_exp2f(-1.4426950408889634f * x);
  return __builtin_amdgcn_rcpf(1.0f + e);
}
__device__ __forceinline__ float tanhf_(float x) {
  float e = __builtin_amdgcn_exp2f(-2.8853900817779268f * x);
  return 2.0f * __builtin_amdgcn_rcpf(1.0f + e) - 1.0f;
}

// ------------------------------------------------------------------
// K1: prep — bf16 converts, token transpose
// ------------------------------------------------------------------
__global__ void k_prep(const float* __restrict__ emb, const float* __restrict__ wih,
                       const float* __restrict__ whh, const int* __restrict__ tok1,
                       const int* __restrict__ tok2, unsigned short* __restrict__ embT,
                       unsigned short* __restrict__ wihb, unsigned short* __restrict__ whhb,
                       int* __restrict__ tokT)
{
  const int stride = gridDim.x * blockDim.x;
  const int id0 = blockIdx.x * blockDim.x + threadIdx.x;
  for (int i = id0; i < VOCAB * EMBD; i += stride) embT[i] = f2bf(emb[i]);
  for (int i = id0; i < G4 * EMBD; i += stride)    wihb[i] = f2bf(wih[i]);
  for (int i = id0; i < G4 * HIDD; i += stride)    whhb[i] = f2bf(whh[i]);
  for (int i = id0; i < 2 * TSEQ * NBAT; i += stride) {
    int l = i >> 17, t = (i >> 8) & 511, n = i & 255;
    tokT[i] = (l ? tok2 : tok1)[n * TSEQ + t];
  }
}

// ------------------------------------------------------------------
// K1b: init h exchange slots (after k_proj — region overlaps dead embT).
// slot 0 (per lstm) = zeros (h(-1)); slots 1..7 = sentinel.
// ------------------------------------------------------------------
__global__ void k_hinit(unsigned long long* __restrict__ hseq)
{
  const int i = blockIdx.x * blockDim.x + threadIdx.x;   // 524288 total
  const int slot = i >> 15;                              // 32768 ull per slot
  hseq[i] = ((slot & 7) == 0) ? 0ull : SENT;
}

// ------------------------------------------------------------------
// K2: vocab projection  P2[v][j*4+g] = emb[v]·W_ih[g*512+j] + b_ih + b_hh
// (unchanged — round-1 correctness-verified)
// ------------------------------------------------------------------
__global__ __launch_bounds__(256) void
k_proj(const unsigned short* __restrict__ embT, const unsigned short* __restrict__ wihb,
       const float* __restrict__ bih, const float* __restrict__ bhh,
       unsigned short* __restrict__ P2)
{
  const int l  = threadIdx.x & 63;
  const int w  = threadIdx.x >> 6;
  const int n0 = blockIdx.x * 128 + (w & 1) * 64;
  const int m0 = blockIdx.y * 128 + (w >> 1) * 64;
  const int lq = l >> 4, lc = l & 15;

  f32x4 acc[4][4];
  #pragma unroll
  for (int a = 0; a < 4; ++a)
    #pragma unroll
    for (int b = 0; b < 4; ++b) acc[a][b] = (f32x4){0.f, 0.f, 0.f, 0.f};

  const uint8_t* eb = (const uint8_t*)embT;
  const uint8_t* wb = (const uint8_t*)wihb;
  #pragma unroll
  for (int ks = 0; ks < 8; ++ks) {
    const int koff = ks * 64 + lq * 16;
    bf16x8 a[4], b[4];
    #pragma unroll
    for (int mt = 0; mt < 4; ++mt) {
      int row = m0 + mt * 16 + lc; if (row >= VOCAB) row = VOCAB - 1;
      a[mt] = *(const bf16x8*)(eb + (size_t)row * 512 + koff);
    }
    #pragma unroll
    for (int nt = 0; nt < 4; ++nt) {
      int g = n0 + nt * 16 + lc;
      b[nt] = *(const bf16x8*)(wb + (size_t)g * 512 + koff);
    }
    #pragma unroll
    for (int mt = 0; mt < 4; ++mt)
      #pragma unroll
      for (int nt = 0; nt < 4; ++nt)
        acc[mt][nt] = __builtin_amdgcn_mfma_f32_16x16x32_bf16(a[mt], b[nt], acc[mt][nt], 0, 0, 0);
  }

  #pragma unroll
  for (int mt = 0; mt < 4; ++mt)
    #pragma unroll
    for (int r = 0; r < 4; ++r) {
      const int vrow = m0 + mt * 16 + lq * 4 + r;
      if (vrow < VOCAB) {
        #pragma unroll
        for (int nt = 0; nt < 4; ++nt) {
          const int gcol = n0 + nt * 16 + lc;
          float v = acc[mt][nt][r] + bih[gcol] + bhh[gcol];
          const int colp = ((gcol & 511) << 2) | (gcol >> 9);  // [j][g] permuted
          P2[(size_t)vrow * 2048 + colp] = f2bf(v);
        }
      }
    }
}

// ------------------------------------------------------------------
// K3: persistent LSTM scan (round-4 structure, sentinel exchange).
// 256 blocks x 256 threads (4 waves). block = (lstm, mg: 32 rows,
// jb: 32 cols). wave = gate. W_hh slice 128KB + h tile 32KB = 160KB LDS.
// h exchange: 8-slot rotating buffers; consumers poll the DATA words
// (64-bit single-copy atomic) against a sentinel — non-sentinel IS the
// payload. Producers re-sentinel slot (t+5)&7 (disjoint mod-8 from all
// active slots under the structural skew bound). No flags, no fences.
// ------------------------------------------------------------------
#define HL 131072

__global__ __launch_bounds__(256, 1) void
k_lstm(const uint8_t* __restrict__ P2, const int* __restrict__ tokT,
       const uint8_t* __restrict__ whh, uint8_t* __restrict__ hseq)
{
  __shared__ __align__(16) uint8_t smem[163840];
  const int tid  = threadIdx.x;
  const int l    = tid & 63;
  const int w    = tid >> 6;        // wave = gate index
  const int bid  = blockIdx.x;
  const int jb   = bid & 15;
  const int mg   = (bid >> 4) & 7;
  const int lstm = bid >> 7;
  const int m0   = mg * 32;
  const int j0   = jb * 32;

  // ---- stage W_hh gate-slice into LDS once, xor-swizzled ----
  // LDS row R = g*32 + jl  <->  W_hh row g*512 + j0 + jl ; 16B chunk c at (c ^ (R&7))
  for (int i = 0; i < 32; ++i) {
    const int G = i * 256 + tid;            // chunk id 0..8191
    const int R = G >> 6, c = G & 63;
    const uint8_t* src = whh + (size_t)((R >> 5) * 512 + j0 + (R & 31)) * 1024 + (size_t)c * 16;
    const uint4 v = *(const uint4*)src;
    *(uint4*)(smem + (size_t)R * 1024 + ((c ^ (R & 7)) * 16)) = v;
  }

  const int em   = tid >> 3;        // epilogue batch row 0..31
  const int ecol = tid & 7;         // epilogue col group (4 cols)
  const int an   = l & 31;          // MFMA A-row / B-col (lane&31)
  const int ah   = l >> 5;          // k-half (lane>>5)
  const int Rrow = w * 32 + an;     // B LDS row

  float cst[4] = {0.f, 0.f, 0.f, 0.f};
  int tok_next = tokT[(lstm * TSEQ + 0) * NBAT + m0 + em];

  for (int t = 0; t < TSEQ; ++t) {
    const int tok_cur = tok_next;

    // ---- issue xg gather + next-token load first (overlaps the poll) ----
    const uint8_t* xsrc = P2 + (size_t)tok_cur * 4096 + (size_t)j0 * 8 + (size_t)ecol * 32;
    const uint4 xq0 = *(const uint4*)(xsrc);
    const uint4 xq1 = *(const uint4*)(xsrc + 16);
    if (t + 1 < TSEQ) tok_next = tokT[(lstm * TSEQ + (t + 1)) * NBAT + m0 + em];

    // ---- poll-stage h(t): sentinel-checked data words -> LDS ----
    {
      const uint8_t* hb = hseq + (size_t)(lstm * 8 + (t & 7)) * HSLOT
                        + (size_t)m0 * 1024 + (size_t)tid * 8;
      unsigned long long v[16];
      #pragma unroll
      for (int i = 0; i < 16; ++i)
        v[i] = __hip_atomic_load((const unsigned long long*)(hb + (size_t)i * 2048),
                                 __ATOMIC_RELAXED, __HIP_MEMORY_SCOPE_AGENT);
      unsigned valid = 0;
      int guard = 0;
      for (;;) {
        #pragma unroll
        for (int i = 0; i < 16; ++i)
          if (!(valid & (1u << i)) && v[i] != SENT) valid |= (1u << i);
        if (valid == 0xFFFFu) break;
        __builtin_amdgcn_s_sleep(1);
        #pragma unroll
        for (int i = 0; i < 16; ++i)
          if (!(valid & (1u << i)))
            v[i] = __hip_atomic_load((const unsigned long long*)(hb + (size_t)i * 2048),
                                     __ATOMIC_RELAXED, __HIP_MEMORY_SCOPE_AGENT);
        if (++guard > 1000000) break;   // fail visible, not hung
      }
      #pragma unroll
      for (int i = 0; i < 16; ++i) {
        const int m = i * 2 + (tid >> 7);
        const int c = (tid >> 1) & 63;
        const int half = tid & 1;
        *(unsigned long long*)(smem + HL + (size_t)m * 1024
                               + ((c ^ (m & 7)) * 16) + half * 8) = v[i];
      }
    }
    __syncthreads();   // h LDS ready (W resident since before t-loop)

    // ---- GEMM: gate_w[32x32] = h[32x512] . W_g[32x512]^T (32x32x16 MFMA) ----
    f32x16 acc0{}, acc1{};
    #pragma unroll 8
    for (int ks = 0; ks < 32; ++ks) {
      const int ch = ks * 2 + ah;
      const bf16x8 av = *(const bf16x8*)(smem + HL + (size_t)an * 1024 + ((ch ^ (an & 7)) * 16));
      const bf16x8 bv = *(const bf16x8*)(smem + (size_t)Rrow * 1024 + ((ch ^ (an & 7)) * 16));
      if (ks & 1) acc1 = __builtin_amdgcn_mfma_f32_32x32x16_bf16(av, bv, acc1, 0, 0, 0);
      else        acc0 = __builtin_amdgcn_mfma_f32_32x32x16_bf16(av, bv, acc0, 0, 0, 0);
    }
    __syncthreads();   // A reads done; h region reusable as f32 gate buffer

    {
      float* gb = (float*)(smem + HL);   // gbuf[g][row 0..31][col 0..31] f32
      #pragma unroll
      for (int r = 0; r < 16; ++r) {
        const int row = (r & 3) + 8 * (r >> 2) + 4 * ah;   // 32x32 C/D mapping
        gb[w * 1024 + row * 32 + an] = acc0[r] + acc1[r];
      }
    }
    __syncthreads();   // gate buffer ready

    // ---- epilogue: 4 cells/lane; h(t+1) -> slot (t+1)&7; re-sentinel (t+5)&7 ----
    {
      const float* gb = (const float*)(smem + HL);
      const f32x4 pi = *(const f32x4*)(gb + 0 * 1024 + em * 32 + ecol * 4);
      const f32x4 pf = *(const f32x4*)(gb + 1 * 1024 + em * 32 + ecol * 4);
      const f32x4 pg = *(const f32x4*)(gb + 2 * 1024 + em * 32 + ecol * 4);
      const f32x4 po = *(const f32x4*)(gb + 3 * 1024 + em * 32 + ecol * 4);
      unsigned short xsv[16];
      *(uint4*)(xsv) = xq0;
      *(uint4*)(xsv + 8) = xq1;
      unsigned short hv[4];
      #pragma unroll
      for (int k = 0; k < 4; ++k) {
        const float iv = sigf(pi[k] + b2f(xsv[k * 4 + 0]));
        const float fv = sigf(pf[k] + b2f(xsv[k * 4 + 1]));
        const float gv = tanhf_(pg[k] + b2f(xsv[k * 4 + 2]));
        const float ov = sigf(po[k] + b2f(xsv[k * 4 + 3]));
        const float cv = fv * cst[k] + iv * gv;
        cst[k] = cv;
        hv[k] = f2bf(ov * tanhf_(cv));
      }
      unsigned long long hp =
          (unsigned long long)hv[0] | ((unsigned long long)hv[1] << 16) |
          ((unsigned long long)hv[2] << 32) | ((unsigned long long)hv[3] << 48);
      const size_t tileoff = (size_t)(m0 + em) * 1024 + (size_t)(j0 + ecol * 4) * 2;
      uint8_t* hdst = hseq + (size_t)(lstm * 8 + ((t + 1) & 7)) * HSLOT + tileoff;
      __hip_atomic_store((unsigned long long*)hdst, hp,
                         __ATOMIC_RELAXED, __HIP_MEMORY_SCOPE_AGENT);
      uint8_t* rdst = hseq + (size_t)(lstm * 8 + ((t + 5) & 7)) * HSLOT + tileoff;
      __hip_atomic_store((unsigned long long*)rdst, SENT,
                         __ATOMIC_RELAXED, __HIP_MEMORY_SCOPE_AGENT);
    }
    __syncthreads();   // WAR guard on gate LDS; also drains vmcnt (bounds reset lag)
  }
}

// ------------------------------------------------------------------
// K4: h1*h2 -> logits -> softmax. one wave per batch row.
// final h(512) lives in slot 512&7 = 0 of each lstm.
// ------------------------------------------------------------------
__global__ __launch_bounds__(64) void
k_fc(const uint8_t* __restrict__ hseq, const float* __restrict__ wfc,
     const float* __restrict__ bfc, float* __restrict__ out)
{
  const int n = blockIdx.x, l = threadIdx.x;
  const unsigned short* h1 = (const unsigned short*)(hseq + (size_t)n * 1024);
  const unsigned short* h2 = (const unsigned short*)(hseq + 8 * HSLOT + (size_t)n * 1024);
  float s0 = 0.f, s1 = 0.f;
  for (int j = l; j < HIDD; j += 64) {
    float hv = b2f(h1[j]) * b2f(h2[j]);
    s0 += hv * wfc[j];
    s1 += hv * wfc[HIDD + j];
  }
  #pragma unroll
  for (int off = 32; off > 0; off >>= 1) {
    s0 += __shfl_down(s0, off, 64);
    s1 += __shfl_down(s1, off, 64);
  }
  if (l == 0) {
    s0 += bfc[0]; s1 += bfc[1];
    float m  = fmaxf(s0, s1);
    float e0 = __builtin_amdgcn_exp2f((s0 - m) * 1.4426950408889634f);
    float e1 = __builtin_amdgcn_exp2f((s1 - m) * 1.4426950408889634f);
    float inv = 1.0f / (e0 + e1);
    out[n * 2 + 0] = e0 * inv;
    out[n * 2 + 1] = e1 * inv;
  }
}

// ------------------------------------------------------------------
extern "C" void kernel_launch(void* const* d_in, const int* in_sizes, int n_in,
                              void* d_out, int out_size, void* d_ws, size_t ws_size,
                              hipStream_t stream) {
  (void)in_sizes; (void)n_in; (void)out_size;
  if (ws_size < WS_NEED) return;   // fail visibly rather than scribble OOB

  const int*   tok1 = (const int*)d_in[0];
  const int*   tok2 = (const int*)d_in[1];
  const float* emb  = (const float*)d_in[2];
  const float* wih  = (const float*)d_in[3];
  const float* whh  = (const float*)d_in[4];
  const float* bih  = (const float*)d_in[5];
  const float* bhh  = (const float*)d_in[6];
  const float* wfc  = (const float*)d_in[7];
  const float* bfc  = (const float*)d_in[8];
  float* out = (float*)d_out;

  uint8_t* ws = (uint8_t*)d_ws;
  unsigned short* P2   = (unsigned short*)(ws + O_P2);
  unsigned short* embT = (unsigned short*)(ws + O_EMBT);
  unsigned short* wihb = (unsigned short*)(ws + O_WIH);
  unsigned short* whhb = (unsigned short*)(ws + O_WHH);
  int*            tokT = (int*)(ws + O_TOKT);
  uint8_t*        hseq = ws + O_HSEQ;

  k_prep<<<1024, 256, 0, stream>>>(emb, wih, whh, tok1, tok2, embT, wihb, whhb, tokT);
  k_proj<<<dim3(16, 391), 256, 0, stream>>>(embT, wihb, bih, bhh, P2);
  k_hinit<<<2048, 256, 0, stream>>>((unsigned long long*)hseq);  // embT dead after k_proj

  {
    const uint8_t* p2p = (const uint8_t*)P2;
    const int*     tkp = tokT;
    const uint8_t* whp = (const uint8_t*)whhb;
    uint8_t*       hsp = hseq;
    void* args[4] = {(void*)&p2p, (void*)&tkp, (void*)&whp, (void*)&hsp};
    hipError_t e = hipLaunchCooperativeKernel((void*)k_lstm, dim3(256), dim3(256),
                                              args, 0, stream);
    if (e != hipSuccess) {
      (void)hipGetLastError();  // clear; fall back (256 blocks @ 1/CU are co-resident)
      k_lstm<<<256, 256, 0, stream>>>(p2p, tkp, whp, hsp);
    }
  }

  k_fc<<<256, 64, 0, stream>>>(hseq, wfc, bfc, out);
}